// Round 6
// baseline (278.173 us; speedup 1.0000x reference)
//
#include <hip/hip_runtime.h>
#include <math.h>

#define B 8
#define S 4096
#define H 1024
#define NSEG 64
#define NPARA 32
#define NA 8
#define BS (B * S)
#define ROWS_PER_BLK 16
#define BLKS_PER_B (S / ROWS_PER_BLK)   // 256
#define NBLK (B * BLKS_PER_B)           // 2048

// online-LSE merge: x = running max, y = running scaled sum
__device__ __forceinline__ float2 lse_merge(float2 A, float2 Bv)
{
    float m = fmaxf(A.x, Bv.x);
    float s = 0.f;
    if (A.y > 0.f)  s += A.y * expf(A.x - m);
    if (Bv.y > 0.f) s += Bv.y * expf(Bv.x - m);
    return make_float2(m, s);
}

__device__ __forceinline__ float blk_reduce1(float v, float* wred1, int t)
{
    const int lane = t & 63, w = t >> 6;
#pragma unroll
    for (int off = 32; off > 0; off >>= 1) v += __shfl_xor(v, off);
    if (lane == 0) wred1[w] = v;
    __syncthreads();
    float r = wred1[0] + wred1[1] + wred1[2] + wred1[3];
    __syncthreads();
    return r;
}

__device__ float listmle_block(const float* fs, const float* fl, float* se,
                               int n, float* wred1, int t)
{
    if (t < n) se[t] = (fl[t] != -1.0f) ? expf(fs[t]) : 0.0f;
    __syncthreads();
    float lp = 0.0f;
    if (t < n && fl[t] >= 0.5f) {
        float fj = fl[t];
        float rest = 0.0f;
        for (int k = 0; k < n; ++k)
            if (fl[k] < fj) rest += se[k];
        lp = fs[t] - logf(se[t] + rest);
    }
    float tot = blk_reduce1(lp, wred1, t);
    return -tot;
}

// ---------------------------------------------------------------------------
// Fused kernel: 2048 blocks, 16 rows each. Streaming dots with packed
// butterfly reduce + fused masked-LSE + segment partials. The LAST block of
// each batch (device-scope counter) runs that batch's tail (LSE merge,
// segment fold, 2x ListMLE, span loss); the globally-last tail writes out.
// ---------------------------------------------------------------------------
__global__ __launch_bounds__(256) void fused_kernel(
    const float4* __restrict__ seq4,
    const float4* __restrict__ Wqa4,     // (H*2/4)
    const float4* __restrict__ Wsp4,     // (H/4)
    const float4* __restrict__ Wrank4,   // (H/4)
    const int*    __restrict__ tt,
    const int*    __restrict__ sent_starts,
    const int*    __restrict__ para_starts,
    const float*  __restrict__ para_labels,
    const float*  __restrict__ sp_labels,
    const int*    __restrict__ starts,
    const int*    __restrict__ ends,
    float4* __restrict__ sc4,            // (B*S) {d0,d1,d_sp,d_rank}
    float4* __restrict__ lse_part,       // (NBLK) {m0,s0,m1,s1}
    float4* __restrict__ segpart,        // (NBLK) {jlo(int),sumA,sumB,0}
    float4* __restrict__ trip,           // (B) {rank, sp, logm, 0}
    int*    __restrict__ counters,       // (B+1), memset to 0 per launch
    float*  __restrict__ out)
{
    const int blk   = blockIdx.x;
    const int b     = blk >> 8;
    const int rbase = (blk & 255) * ROWS_PER_BLK;
    const int t     = threadIdx.x;
    const int w     = t >> 6, lane = t & 63;

    __shared__ int    ssh[NSEG + 1];
    __shared__ int    rowseg[ROWS_PER_BLK];
    __shared__ int    ttsh[ROWS_PER_BLK];
    __shared__ float4 lsep[4];
    __shared__ float2 wacc[4];
    __shared__ int    jlo_sh;
    __shared__ int    is_last;
    // tail-only:
    __shared__ float4 lsew[4];
    __shared__ float  segsum[NSEG + 2];
    __shared__ float  wred1[4];
    __shared__ float  fsb[1 + NSEG], flb[1 + NSEG], seb[1 + NSEG];
    __shared__ float  lse_sh[2];

    // ---- weight preload (all float4; lane covers chunk lane+64c) ------------
    float4 qA[4], qB[4], spv[4], rkv[4];
#pragma unroll
    for (int c = 0; c < 4; ++c) {
        const int ch = lane + 64 * c;
        qA[c]  = Wqa4[ch * 2];       // {W[h][0],W[h][1],W[h+1][0],W[h+1][1]}
        qB[c]  = Wqa4[ch * 2 + 1];   // h+2, h+3
        spv[c] = Wsp4[ch];
        rkv[c] = Wrank4[ch];
    }

    // ---- per-block tables ----------------------------------------------------
    if (t < NSEG + 1) ssh[t] = sent_starts[b * (NSEG + 1) + t];
    __syncthreads();
    if (t < ROWS_PER_BLK) {
        ttsh[t] = tt[b * S + rbase + t];
        const int r = rbase + t;
        int j = -1;
        for (int k = 0; k < NSEG; ++k) {
            int en = ssh[k + 1];
            if (en == -1) break;
            if (r >= ssh[k] && r < en) { j = k; break; }
        }
        rowseg[t] = j;
    }
    __syncthreads();
    if (t == 0) {
        int jl = -1;
        for (int i = 0; i < ROWS_PER_BLK; ++i)
            if (rowseg[i] >= 0) { jl = rowseg[i]; break; }
        jlo_sh = jl;
    }
    __syncthreads();
    const int jlo = jlo_sh;

    // ---- streaming dots: 4 rows per wave, packed butterfly reduce -----------
    const float4* base = seq4 + (size_t)(b * S + rbase) * (H / 4);
    float mm = -INFINITY, ssum = 0.f;        // lane0: start-LSE; lane1: end-LSE
    float segA = 0.f, segB = 0.f;            // lane2: d_sp segment partials

#pragma unroll
    for (int g = 0; g < 4; ++g) {
        const int lrow = g * 4 + w;
        const float4* rp = base + (size_t)lrow * (H / 4);
        float a0 = 0.f, a1 = 0.f, a2 = 0.f, a3 = 0.f;
#pragma unroll
        for (int c = 0; c < 4; ++c) {
            float4 v = rp[lane + 64 * c];
            a0 += v.x * qA[c].x + v.y * qA[c].z + v.z * qB[c].x + v.w * qB[c].z;
            a1 += v.x * qA[c].y + v.y * qA[c].w + v.z * qB[c].y + v.w * qB[c].w;
            a2 += v.x * spv[c].x + v.y * spv[c].y + v.z * spv[c].z + v.w * spv[c].w;
            a3 += v.x * rkv[c].x + v.y * rkv[c].y + v.z * rkv[c].z + v.w * rkv[c].w;
        }
        // fold 4 accumulators into lane classes (lane&3): 0->a0,1->a1,2->a2,3->a3
        float u01 = (lane & 1) ? a0 : a1;
        float x01 = ((lane & 1) ? a1 : a0) + __shfl_xor(u01, 1);
        float u23 = (lane & 1) ? a2 : a3;
        float x23 = ((lane & 1) ? a3 : a2) + __shfl_xor(u23, 1);
        float uu  = (lane & 2) ? x01 : x23;
        float x   = ((lane & 2) ? x23 : x01) + __shfl_xor(uu, 2);
#pragma unroll
        for (int off = 4; off < 64; off <<= 1) x += __shfl_xor(x, off);
        // x = full row-dot of this lane's class
        if (ttsh[lrow] == 1) {               // lanes 0/1 track start/end LSE
            float mn = fmaxf(mm, x);
            ssum = ssum * expf(mm - mn) + expf(x - mn);
            mm = mn;
        }
        const int j = rowseg[lrow];          // lane 2 tracks segment sums
        if (j >= 0) { if (j == jlo) segA += x; else segB += x; }
        if (lane < 4)
            ((float*)(sc4 + (size_t)b * S + rbase + lrow))[lane] = x;
    }

    {
        float mE = __shfl(mm, 1),   sE = __shfl(ssum, 1);
        float sa = __shfl(segA, 2), sb = __shfl(segB, 2);
        if (lane == 0) {
            lsep[w] = make_float4(mm, ssum, mE, sE);
            wacc[w] = make_float2(sa, sb);
        }
    }
    __syncthreads();
    if (t == 0) {
        float2 L0 = make_float2(lsep[0].x, lsep[0].y);
        float2 L1 = make_float2(lsep[0].z, lsep[0].w);
        float SA = wacc[0].x, SB = wacc[0].y;
#pragma unroll
        for (int i = 1; i < 4; ++i) {
            L0 = lse_merge(L0, make_float2(lsep[i].x, lsep[i].y));
            L1 = lse_merge(L1, make_float2(lsep[i].z, lsep[i].w));
            SA += wacc[i].x; SB += wacc[i].y;
        }
        lse_part[blk] = make_float4(L0.x, L0.y, L1.x, L1.y);
        segpart[blk]  = make_float4(__int_as_float(jlo), SA, SB, 0.f);
    }

    // ---- last-block-of-batch election ----------------------------------------
    __threadfence();                          // flush this thread's writes
    __syncthreads();                          // all threads fenced
    if (t == 0)
        is_last = (atomicAdd(&counters[b], 1) == BLKS_PER_B - 1) ? 1 : 0;
    __syncthreads();
    if (!is_last) return;
    __threadfence();                          // acquire other blocks' writes

    // ======================= batch tail (one block) ===========================
    // (a) merge 256 LSE partials
    {
        float4 P = lse_part[(size_t)b * BLKS_PER_B + t];
        float2 L0 = make_float2(P.x, P.y);
        float2 L1 = make_float2(P.z, P.w);
#pragma unroll
        for (int off = 32; off > 0; off >>= 1) {
            float2 O0 = make_float2(__shfl_xor(L0.x, off), __shfl_xor(L0.y, off));
            float2 O1 = make_float2(__shfl_xor(L1.x, off), __shfl_xor(L1.y, off));
            L0 = lse_merge(L0, O0);
            L1 = lse_merge(L1, O1);
        }
        if (lane == 0) lsew[w] = make_float4(L0.x, L0.y, L1.x, L1.y);
    }
    if (t < NSEG + 2) segsum[t] = 0.f;
    __syncthreads();

    // (b) fold 256 segment partials + finalize LSE
    {
        float4 SP = segpart[(size_t)b * BLKS_PER_B + t];
        int jl = __float_as_int(SP.x);
        if (jl >= 0) {
            atomicAdd(&segsum[jl], SP.y);
            atomicAdd(&segsum[jl + 1], SP.z);
        }
    }
    if (t == 0) {
        float2 M0 = make_float2(lsew[0].x, lsew[0].y);
        float2 M1 = make_float2(lsew[0].z, lsew[0].w);
#pragma unroll
        for (int i = 1; i < 4; ++i) {
            M0 = lse_merge(M0, make_float2(lsew[i].x, lsew[i].y));
            M1 = lse_merge(M1, make_float2(lsew[i].z, lsew[i].w));
        }
        lse_sh[0] = M0.x + logf(M0.y);
        lse_sh[1] = M1.x + logf(M1.y);
    }
    __syncthreads();

    // (c) sp ListMLE
    if (t == 0) { fsb[0] = sc4[(size_t)b * S].z; flb[0] = 0.5f; }
    if (t < NSEG) {
        int st = ssh[t];
        int en = ssh[t + 1];
        float score;
        if (en != -1) {
            int stc = min(max(st, 0), S);
            int enc = max(min(max(en, 0), S), stc + 1);
            score = segsum[t] / (float)(enc - stc);
        } else {
            score = sc4[(size_t)b * S + S - 1].z;   // d_sp at last row
        }
        fsb[1 + t] = score;
        flb[1 + t] = sp_labels[b * NSEG + t];
    }
    __syncthreads();
    float sp_loss_b = listmle_block(fsb, flb, seb, 1 + NSEG, wred1, t);

    // (d) rank ListMLE
    if (t == 0) { fsb[0] = sc4[(size_t)b * S].w; flb[0] = 0.5f; }
    if (t < NPARA) {
        int ps = para_starts[b * NPARA + t];
        fsb[1 + t] = sc4[(size_t)b * S + ps].w;
        flb[1 + t] = para_labels[b * NPARA + t];
    }
    __syncthreads();
    float rank_loss_b = listmle_block(fsb, flb, seb, 1 + NPARA, wred1, t);

    // (e) span loss (parallel over answers)
    float e_a = 0.f;
    if (t < NA) {
        const float lse0 = lse_sh[0], lse1 = lse_sh[1];
        int tsv = starts[b * NA + t];
        int tev = ends[b * NA + t];
        float lt = 0.f;
        if (tsv != -1) {
            int sf = min(max(tsv, 0), S - 1);
            float sl = (tt[b * S + sf] == 1) ? sc4[(size_t)b * S + sf].x : -INFINITY;
            lt += -(sl - lse0);
        }
        if (tev != -1) {
            int sf = min(max(tev, 0), S - 1);
            float el = (tt[b * S + sf] == 1) ? sc4[(size_t)b * S + sf].y : -INFINITY;
            lt += -(el - lse1);
        }
        float lp = -lt;
        e_a = (lp == 0.0f) ? 0.f : expf(lp);
    }
#pragma unroll
    for (int off = 4; off > 0; off >>= 1) e_a += __shfl_xor(e_a, off, 8);

    // (f) per-batch triple; globally-last tail writes the output
    if (t == 0) {
        float logm = (e_a > 0.f) ? logf(e_a) : 0.f;
        trip[b] = make_float4(rank_loss_b, sp_loss_b, logm, 0.f);
        __threadfence();
        if (atomicAdd(&counters[B], 1) == B - 1) {
            __threadfence();
            float rk = 0.f, sp = 0.f, sl = 0.f;
            for (int i = 0; i < B; ++i) {
                float4 T = trip[i];
                rk += T.x; sp += T.y; sl += T.z;
            }
            out[0] = rk + sp - sl;   // span_loss = -sum(logm)
            out[1] = rk;
            out[2] = sp;
        }
    }
}

extern "C" void kernel_launch(void* const* d_in, const int* in_sizes, int n_in,
                              void* d_out, int out_size, void* d_ws, size_t ws_size,
                              hipStream_t stream)
{
    const float* seq         = (const float*)d_in[0];
    const int*   tt          = (const int*)  d_in[1];
    const int*   sent_starts = (const int*)  d_in[2];
    const int*   para_starts = (const int*)  d_in[3];
    const float* para_labels = (const float*)d_in[4];
    const float* sp_labels   = (const float*)d_in[5];
    const int*   starts      = (const int*)  d_in[6];
    const int*   ends        = (const int*)  d_in[7];
    const float* Wqa         = (const float*)d_in[8];
    const float* Wrank       = (const float*)d_in[10];
    const float* Wsp         = (const float*)d_in[12];

    float*  out      = (float*)d_out;
    float4* sc4      = (float4*)d_ws;            // B*S float4 = 512 KB
    float4* lse_part = sc4 + (size_t)BS;         // NBLK
    float4* segpart  = lse_part + NBLK;          // NBLK
    float4* trip     = segpart + NBLK;           // B
    int*    counters = (int*)(trip + B);         // B+1 ints

    hipMemsetAsync(counters, 0, (B + 1) * sizeof(int), stream);
    fused_kernel<<<NBLK, 256, 0, stream>>>((const float4*)seq,
                                           (const float4*)Wqa,
                                           (const float4*)Wsp,
                                           (const float4*)Wrank,
                                           tt, sent_starts, para_starts,
                                           para_labels, sp_labels,
                                           starts, ends,
                                           sc4, lse_part, segpart, trip,
                                           counters, out);
}

// Round 7
// 42.075 us; speedup vs baseline: 6.6114x; 6.6114x over previous
//
#include <hip/hip_runtime.h>
#include <math.h>

#define B 8
#define S 4096
#define H 1024
#define NSEG 64
#define NPARA 32
#define NA 8
#define BS (B * S)
#define ROWS_PER_BLK 16
#define BLKS_PER_B (S / ROWS_PER_BLK)   // 256
#define NBLK (B * BLKS_PER_B)           // 2048

// online-LSE merge: x = running max, y = running scaled sum
__device__ __forceinline__ float2 lse_merge(float2 A, float2 Bv)
{
    float m = fmaxf(A.x, Bv.x);
    float s = 0.f;
    if (A.y > 0.f)  s += A.y * expf(A.x - m);
    if (Bv.y > 0.f) s += Bv.y * expf(Bv.x - m);
    return make_float2(m, s);
}

// ---------------------------------------------------------------------------
// Kernel 1: streaming per-row 4-way dots, 16 rows/block, packed butterfly
// reduce (7 shuffles), fused masked-LSE partials (lanes 0/1) and d_sp
// segment partial sums (lane 2; block spans <= 2 segments). No fences.
// ---------------------------------------------------------------------------
__global__ __launch_bounds__(256) void dots_kernel(
    const float4* __restrict__ seq4,
    const float4* __restrict__ Wqa4,     // (H*2/4)
    const float4* __restrict__ Wsp4,     // (H/4)
    const float4* __restrict__ Wrank4,   // (H/4)
    const int*    __restrict__ tt,
    const int*    __restrict__ sent_starts,
    float4* __restrict__ sc4,            // (B*S) {d0,d1,d_sp,d_rank}
    float4* __restrict__ lse_part,       // (NBLK) {m0,s0,m1,s1}
    float4* __restrict__ segpart,        // (NBLK) {jlo(int),sumA,sumB,0}
    float*  __restrict__ out)
{
    const int blk   = blockIdx.x;
    const int b     = blk >> 8;
    const int rbase = (blk & 255) * ROWS_PER_BLK;
    const int t     = threadIdx.x;
    const int w     = t >> 6, lane = t & 63;

    if (blk == 0 && t == 0) { out[0] = 0.f; out[1] = 0.f; out[2] = 0.f; }

    __shared__ int    ssh[NSEG + 1];
    __shared__ int    rowseg[ROWS_PER_BLK];
    __shared__ int    ttsh[ROWS_PER_BLK];
    __shared__ float4 lsep[4];
    __shared__ float2 wacc[4];
    __shared__ int    jlo_sh;

    // ---- weight preload (all float4; lane covers chunk lane+64c) ------------
    float4 qA[4], qB[4], spv[4], rkv[4];
#pragma unroll
    for (int c = 0; c < 4; ++c) {
        const int ch = lane + 64 * c;
        qA[c]  = Wqa4[ch * 2];       // {W[h][0],W[h][1],W[h+1][0],W[h+1][1]}
        qB[c]  = Wqa4[ch * 2 + 1];   // h+2, h+3
        spv[c] = Wsp4[ch];
        rkv[c] = Wrank4[ch];
    }

    // ---- per-block tables ----------------------------------------------------
    if (t < NSEG + 1) ssh[t] = sent_starts[b * (NSEG + 1) + t];
    __syncthreads();
    if (t < ROWS_PER_BLK) {
        ttsh[t] = tt[b * S + rbase + t];
        const int r = rbase + t;
        int j = -1;
        for (int k = 0; k < NSEG; ++k) {
            int en = ssh[k + 1];
            if (en == -1) break;
            if (r >= ssh[k] && r < en) { j = k; break; }
        }
        rowseg[t] = j;
    }
    __syncthreads();
    if (t == 0) {
        int jl = -1;
        for (int i = 0; i < ROWS_PER_BLK; ++i)
            if (rowseg[i] >= 0) { jl = rowseg[i]; break; }
        jlo_sh = jl;
    }
    __syncthreads();
    const int jlo = jlo_sh;

    // ---- streaming dots: 4 rows per wave, packed butterfly reduce -----------
    const float4* base = seq4 + (size_t)(b * S + rbase) * (H / 4);
    float mm = -INFINITY, ssum = 0.f;        // lane0: start-LSE; lane1: end-LSE
    float segA = 0.f, segB = 0.f;            // lane2: d_sp segment partials

#pragma unroll
    for (int g = 0; g < 4; ++g) {
        const int lrow = g * 4 + w;
        const float4* rp = base + (size_t)lrow * (H / 4);
        float a0 = 0.f, a1 = 0.f, a2 = 0.f, a3 = 0.f;
#pragma unroll
        for (int c = 0; c < 4; ++c) {
            float4 v = rp[lane + 64 * c];
            a0 += v.x * qA[c].x + v.y * qA[c].z + v.z * qB[c].x + v.w * qB[c].z;
            a1 += v.x * qA[c].y + v.y * qA[c].w + v.z * qB[c].y + v.w * qB[c].w;
            a2 += v.x * spv[c].x + v.y * spv[c].y + v.z * spv[c].z + v.w * spv[c].w;
            a3 += v.x * rkv[c].x + v.y * rkv[c].y + v.z * rkv[c].z + v.w * rkv[c].w;
        }
        // fold 4 accumulators into lane classes (lane&3): 0->a0,1->a1,2->a2,3->a3
        float u01 = (lane & 1) ? a0 : a1;
        float x01 = ((lane & 1) ? a1 : a0) + __shfl_xor(u01, 1);
        float u23 = (lane & 1) ? a2 : a3;
        float x23 = ((lane & 1) ? a3 : a2) + __shfl_xor(u23, 1);
        float uu  = (lane & 2) ? x01 : x23;
        float x   = ((lane & 2) ? x23 : x01) + __shfl_xor(uu, 2);
#pragma unroll
        for (int off = 4; off < 64; off <<= 1) x += __shfl_xor(x, off);
        // x = full row-dot of this lane's class
        if (ttsh[lrow] == 1) {               // lanes 0/1 track start/end LSE
            float mn = fmaxf(mm, x);
            ssum = ssum * expf(mm - mn) + expf(x - mn);
            mm = mn;
        }
        const int j = rowseg[lrow];          // lane 2 tracks segment sums
        if (j >= 0) { if (j == jlo) segA += x; else segB += x; }
        if (lane < 4)
            ((float*)(sc4 + (size_t)b * S + rbase + lrow))[lane] = x;
    }

    {
        float mE = __shfl(mm, 1),   sE = __shfl(ssum, 1);
        float sa = __shfl(segA, 2), sb = __shfl(segB, 2);
        if (lane == 0) {
            lsep[w] = make_float4(mm, ssum, mE, sE);
            wacc[w] = make_float2(sa, sb);
        }
    }
    __syncthreads();
    if (t == 0) {
        float2 L0 = make_float2(lsep[0].x, lsep[0].y);
        float2 L1 = make_float2(lsep[0].z, lsep[0].w);
        float SA = wacc[0].x, SB = wacc[0].y;
#pragma unroll
        for (int i = 1; i < 4; ++i) {
            L0 = lse_merge(L0, make_float2(lsep[i].x, lsep[i].y));
            L1 = lse_merge(L1, make_float2(lsep[i].z, lsep[i].w));
            SA += wacc[i].x; SB += wacc[i].y;
        }
        lse_part[blk] = make_float4(L0.x, L0.y, L1.x, L1.y);
        segpart[blk]  = make_float4(__int_as_float(jlo), SA, SB, 0.f);
    }
}

// ---------------------------------------------------------------------------
// block reduce (sum) for ListMLE
// ---------------------------------------------------------------------------
__device__ __forceinline__ float blk_reduce1(float v, float* wred1, int t)
{
    const int lane = t & 63, w = t >> 6;
#pragma unroll
    for (int off = 32; off > 0; off >>= 1) v += __shfl_xor(v, off);
    if (lane == 0) wred1[w] = v;
    __syncthreads();
    float r = wred1[0] + wred1[1] + wred1[2] + wred1[3];
    __syncthreads();
    return r;
}

__device__ float listmle_block(const float* fs, const float* fl, float* se,
                               int n, float* wred1, int t)
{
    if (t < n) se[t] = (fl[t] != -1.0f) ? expf(fs[t]) : 0.0f;
    __syncthreads();
    float lp = 0.0f;
    if (t < n && fl[t] >= 0.5f) {
        float fj = fl[t];
        float rest = 0.0f;
        for (int k = 0; k < n; ++k)
            if (fl[k] < fj) rest += se[k];
        lp = fs[t] - logf(se[t] + rest);
    }
    float tot = blk_reduce1(lp, wred1, t);
    return -tot;
}

// ---------------------------------------------------------------------------
// Kernel 2: one block per batch. Merge 256 LSE partials, fold 256 segment
// partials (LDS atomics), 2x ListMLE, span loss; atomicAdd into out.
// ---------------------------------------------------------------------------
__global__ __launch_bounds__(256) void batch_kernel(
    const float4* __restrict__ sc4,
    const float4* __restrict__ lse_part,
    const float4* __restrict__ segpart,
    const int*    __restrict__ tt,
    const int*    __restrict__ sent_starts,
    const int*    __restrict__ para_starts,
    const float*  __restrict__ para_labels,
    const float*  __restrict__ sp_labels,
    const int*    __restrict__ starts,
    const int*    __restrict__ ends,
    float* __restrict__ out)
{
    const int b = blockIdx.x;
    const int t = threadIdx.x;
    const int lane = t & 63, w = t >> 6;

    __shared__ float4 lsew[4];
    __shared__ float  segsum[NSEG + 2];
    __shared__ int    ssh[NSEG + 1];
    __shared__ float  wred1[4];
    __shared__ float  fsb[1 + NSEG], flb[1 + NSEG], seb[1 + NSEG];
    __shared__ float  lse_sh[2];

    const float4* sb  = sc4 + (size_t)b * S;
    const int*    ttb = tt + b * S;

    if (t < NSEG + 2) segsum[t] = 0.f;
    if (t < NSEG + 1) ssh[t] = sent_starts[b * (NSEG + 1) + t];
    __syncthreads();

    // ---- merge 256 LSE partials + fold 256 segment partials -----------------
    {
        float4 P = lse_part[(size_t)b * BLKS_PER_B + t];
        float2 L0 = make_float2(P.x, P.y);
        float2 L1 = make_float2(P.z, P.w);
#pragma unroll
        for (int off = 32; off > 0; off >>= 1) {
            float2 O0 = make_float2(__shfl_xor(L0.x, off), __shfl_xor(L0.y, off));
            float2 O1 = make_float2(__shfl_xor(L1.x, off), __shfl_xor(L1.y, off));
            L0 = lse_merge(L0, O0);
            L1 = lse_merge(L1, O1);
        }
        if (lane == 0) lsew[w] = make_float4(L0.x, L0.y, L1.x, L1.y);

        float4 SP = segpart[(size_t)b * BLKS_PER_B + t];
        int jl = __float_as_int(SP.x);
        if (jl >= 0) {
            atomicAdd(&segsum[jl], SP.y);
            atomicAdd(&segsum[jl + 1], SP.z);
        }
    }
    __syncthreads();
    if (t == 0) {
        float2 M0 = make_float2(lsew[0].x, lsew[0].y);
        float2 M1 = make_float2(lsew[0].z, lsew[0].w);
#pragma unroll
        for (int i = 1; i < 4; ++i) {
            M0 = lse_merge(M0, make_float2(lsew[i].x, lsew[i].y));
            M1 = lse_merge(M1, make_float2(lsew[i].z, lsew[i].w));
        }
        lse_sh[0] = M0.x + logf(M0.y);
        lse_sh[1] = M1.x + logf(M1.y);
    }

    // ---- sp ListMLE ---------------------------------------------------------
    if (t == 0) { fsb[0] = sb[0].z; flb[0] = 0.5f; }       // sent_thres
    if (t < NSEG) {
        int st = ssh[t];
        int en = ssh[t + 1];
        float score;
        if (en != -1) {
            int stc = min(max(st, 0), S);
            int enc = max(min(max(en, 0), S), stc + 1);
            score = segsum[t] / (float)(enc - stc);
        } else {
            score = sb[S - 1].z;                           // d_sp at last row
        }
        fsb[1 + t] = score;
        flb[1 + t] = sp_labels[b * NSEG + t];
    }
    __syncthreads();
    float sp_loss_b = listmle_block(fsb, flb, seb, 1 + NSEG, wred1, t);

    // ---- rank ListMLE -------------------------------------------------------
    if (t == 0) { fsb[0] = sb[0].w; flb[0] = 0.5f; }       // rank_thres
    if (t < NPARA) {
        int ps = para_starts[b * NPARA + t];
        fsb[1 + t] = sb[ps].w;
        flb[1 + t] = para_labels[b * NPARA + t];
    }
    __syncthreads();
    float rank_loss_b = listmle_block(fsb, flb, seb, 1 + NPARA, wred1, t);

    // ---- span loss (parallel over answers) ----------------------------------
    float e_a = 0.f;
    if (t < NA) {
        const float lse0 = lse_sh[0], lse1 = lse_sh[1];
        int tsv = starts[b * NA + t];
        int tev = ends[b * NA + t];
        float lt = 0.f;
        if (tsv != -1) {
            int sf = min(max(tsv, 0), S - 1);
            float sl = (ttb[sf] == 1) ? sb[sf].x : -INFINITY;
            lt += -(sl - lse0);
        }
        if (tev != -1) {
            int sf = min(max(tev, 0), S - 1);
            float el = (ttb[sf] == 1) ? sb[sf].y : -INFINITY;
            lt += -(el - lse1);
        }
        float lp = -lt;
        e_a = (lp == 0.0f) ? 0.f : expf(lp);
    }
#pragma unroll
    for (int off = 4; off > 0; off >>= 1) e_a += __shfl_xor(e_a, off, 8);
    if (t == 0) {
        float logm = (e_a > 0.f) ? logf(e_a) : 0.f;
        atomicAdd(out + 0, rank_loss_b + sp_loss_b - logm);
        atomicAdd(out + 1, rank_loss_b);
        atomicAdd(out + 2, sp_loss_b);
    }
}

extern "C" void kernel_launch(void* const* d_in, const int* in_sizes, int n_in,
                              void* d_out, int out_size, void* d_ws, size_t ws_size,
                              hipStream_t stream)
{
    const float* seq         = (const float*)d_in[0];
    const int*   tt          = (const int*)  d_in[1];
    const int*   sent_starts = (const int*)  d_in[2];
    const int*   para_starts = (const int*)  d_in[3];
    const float* para_labels = (const float*)d_in[4];
    const float* sp_labels   = (const float*)d_in[5];
    const int*   starts      = (const int*)  d_in[6];
    const int*   ends        = (const int*)  d_in[7];
    const float* Wqa         = (const float*)d_in[8];
    const float* Wrank       = (const float*)d_in[10];
    const float* Wsp         = (const float*)d_in[12];

    float*  out      = (float*)d_out;
    float4* sc4      = (float4*)d_ws;            // B*S float4 = 512 KB
    float4* lse_part = sc4 + (size_t)BS;         // NBLK
    float4* segpart  = lse_part + NBLK;          // NBLK

    dots_kernel<<<NBLK, 256, 0, stream>>>((const float4*)seq,
                                          (const float4*)Wqa,
                                          (const float4*)Wsp,
                                          (const float4*)Wrank,
                                          tt, sent_starts,
                                          sc4, lse_part, segpart, out);
    batch_kernel<<<B, 256, 0, stream>>>(sc4, lse_part, segpart, tt, sent_starts,
                                        para_starts, para_labels, sp_labels,
                                        starts, ends, out);
}